// Round 1
// baseline (1579.095 us; speedup 1.0000x reference)
//
#include <hip/hip_runtime.h>

#define NN 50000
#define EE 800000
#define GG 64

// ---------------- CSR build ----------------

__global__ void hist_kernel(const int* __restrict__ ei, int* __restrict__ deg) {
    int e = blockIdx.x * 256 + threadIdx.x;
    if (e < EE) atomicAdd(&deg[ei[EE + e]], 1);
}

__global__ void scan1_kernel(const int* __restrict__ deg, int* __restrict__ offs,
                             int* __restrict__ bsum) {
    __shared__ int lds[1024];
    int i = blockIdx.x * 1024 + threadIdx.x;
    int v = (i < NN) ? deg[i] : 0;
    lds[threadIdx.x] = v;
    __syncthreads();
    for (int d = 1; d < 1024; d <<= 1) {
        int t = (threadIdx.x >= d) ? lds[threadIdx.x - d] : 0;
        __syncthreads();
        lds[threadIdx.x] += t;
        __syncthreads();
    }
    int incl = lds[threadIdx.x];
    if (i < NN) offs[i] = incl - v;  // exclusive within block
    if (threadIdx.x == 1023) bsum[blockIdx.x] = incl;
}

__global__ void scan2_kernel(int* bsum, int nb) {
    if (threadIdx.x == 0 && blockIdx.x == 0) {
        int run = 0;
        for (int b = 0; b < nb; ++b) { int t = bsum[b]; bsum[b] = run; run += t; }
    }
}

__global__ void scan3_kernel(int* __restrict__ offs, int* __restrict__ cursor,
                             const int* __restrict__ bsum) {
    int i = blockIdx.x * 1024 + threadIdx.x;
    if (i < NN) {
        int o = offs[i] + bsum[blockIdx.x];
        offs[i] = o;
        cursor[i] = o;
    }
    if (i == 0 && blockIdx.x == 0) offs[NN] = EE;
}

__global__ void scatter_kernel(const int* __restrict__ ei, int* __restrict__ cursor,
                               int* __restrict__ srcs) {
    int e = blockIdx.x * 256 + threadIdx.x;
    if (e < EE) {
        int s = ei[e];
        int d = ei[EE + e];
        int pos = atomicAdd(&cursor[d], 1);
        srcs[pos] = s;
    }
}

// ---------------- GIN aggregation: h0 = (1+eps)*x + sum_{src->node} x[src] ----------------
// one wave (64 lanes) per node, float2 per lane covers 128 dims

__global__ void agg_kernel(const float* __restrict__ x, const int* __restrict__ offs,
                           const int* __restrict__ srcs, const float* __restrict__ epsp,
                           int layer, float* __restrict__ h0) {
    int node = blockIdx.x * 4 + (threadIdx.x >> 6);
    if (node >= NN) return;
    int lane = threadIdx.x & 63;
    int beg = offs[node], end = offs[node + 1];
    float a0 = 0.f, a1 = 0.f;
    for (int i = beg; i < end; ++i) {
        int s = srcs[i];
        const float2 v = *(const float2*)(x + (size_t)s * 128 + lane * 2);
        a0 += v.x; a1 += v.y;
    }
    float e1 = 1.0f + epsp[layer];
    const float2 xv = *(const float2*)(x + (size_t)node * 128 + lane * 2);
    float2 o;
    o.x = fmaf(e1, xv.x, a0);
    o.y = fmaf(e1, xv.y, a1);
    *(float2*)(h0 + (size_t)node * 128 + lane * 2) = o;
}

// ---------------- GEMM1: y1 = h0 (N x 128) @ W (128 x 64), raw output ----------------

__global__ __launch_bounds__(256, 1) void gemm1_kernel(const float* __restrict__ h0,
                                                       const float* __restrict__ W,
                                                       float* __restrict__ y) {
    __shared__ float lW[128 * 64];
    for (int t = threadIdx.x; t < 2048; t += 256)
        ((float4*)lW)[t] = ((const float4*)W)[t];
    __syncthreads();
    int n = blockIdx.x * 256 + threadIdx.x;
    if (n >= NN) return;
    float acc[64];
#pragma unroll
    for (int j = 0; j < 64; ++j) acc[j] = 0.f;
    const float4* xr = (const float4*)(h0 + (size_t)n * 128);
#pragma unroll 1
    for (int k4 = 0; k4 < 32; ++k4) {
        float4 xv = xr[k4];
#pragma unroll
        for (int kk = 0; kk < 4; ++kk) {
            float xk = (kk == 0) ? xv.x : (kk == 1) ? xv.y : (kk == 2) ? xv.z : xv.w;
            const float4* wr = (const float4*)(lW + (k4 * 4 + kk) * 64);
#pragma unroll
            for (int j = 0; j < 16; ++j) {
                float4 wv = wr[j];
                acc[4 * j + 0] = fmaf(xk, wv.x, acc[4 * j + 0]);
                acc[4 * j + 1] = fmaf(xk, wv.y, acc[4 * j + 1]);
                acc[4 * j + 2] = fmaf(xk, wv.z, acc[4 * j + 2]);
                acc[4 * j + 3] = fmaf(xk, wv.w, acc[4 * j + 3]);
            }
        }
    }
    float4* yr = (float4*)(y + (size_t)n * 64);
#pragma unroll
    for (int j = 0; j < 16; ++j)
        yr[j] = make_float4(acc[4 * j], acc[4 * j + 1], acc[4 * j + 2], acc[4 * j + 3]);
}

// ---------------- GEMM2: y2 = relu(bn1(y1)) (N x 64) @ W (64 x 128), raw output ----------------

__global__ __launch_bounds__(256, 1) void gemm2_kernel(const float* __restrict__ y1,
                                                       const float* __restrict__ W,
                                                       const float* __restrict__ sb,
                                                       float* __restrict__ y2) {
    __shared__ float lW[64 * 128];
    for (int t = threadIdx.x; t < 2048; t += 256)
        ((float4*)lW)[t] = ((const float4*)W)[t];
    __syncthreads();
    int n = blockIdx.x * 256 + threadIdx.x;
    if (n >= NN) return;
    float acc[128];
#pragma unroll
    for (int j = 0; j < 128; ++j) acc[j] = 0.f;
    const float4* xr = (const float4*)(y1 + (size_t)n * 64);
#pragma unroll 1
    for (int k4 = 0; k4 < 16; ++k4) {
        float4 xv = xr[k4];
#pragma unroll
        for (int kk = 0; kk < 4; ++kk) {
            int k = k4 * 4 + kk;
            float raw = (kk == 0) ? xv.x : (kk == 1) ? xv.y : (kk == 2) ? xv.z : xv.w;
            float v = fmaxf(fmaf(raw, sb[k], sb[128 + k]), 0.f);
            const float4* wr = (const float4*)(lW + k * 128);
#pragma unroll
            for (int j = 0; j < 32; ++j) {
                float4 wv = wr[j];
                acc[4 * j + 0] = fmaf(v, wv.x, acc[4 * j + 0]);
                acc[4 * j + 1] = fmaf(v, wv.y, acc[4 * j + 1]);
                acc[4 * j + 2] = fmaf(v, wv.z, acc[4 * j + 2]);
                acc[4 * j + 3] = fmaf(v, wv.w, acc[4 * j + 3]);
            }
        }
    }
    float4* yr = (float4*)(y2 + (size_t)n * 128);
#pragma unroll
    for (int j = 0; j < 32; ++j)
        yr[j] = make_float4(acc[4 * j], acc[4 * j + 1], acc[4 * j + 2], acc[4 * j + 3]);
}

// ---------------- last layer: x = relu( relu(bn1(y1)) @ Wlast (64 x 2) ) ----------------

__global__ void gemm_last_kernel(const float* __restrict__ y1, const float* __restrict__ W,
                                 const float* __restrict__ sb, float* __restrict__ xl) {
    __shared__ float lw[128];
    if (threadIdx.x < 128) lw[threadIdx.x] = W[threadIdx.x];
    __syncthreads();
    int n = blockIdx.x * 256 + threadIdx.x;
    if (n >= NN) return;
    float a0 = 0.f, a1 = 0.f;
    const float* row = y1 + (size_t)n * 64;
#pragma unroll
    for (int k = 0; k < 64; ++k) {
        float v = fmaxf(fmaf(row[k], sb[k], sb[128 + k]), 0.f);
        a0 = fmaf(v, lw[2 * k + 0], a0);
        a1 = fmaf(v, lw[2 * k + 1], a1);
    }
    xl[2 * n + 0] = fmaxf(a0, 0.f);
    xl[2 * n + 1] = fmaxf(a1, 0.f);
}

// ---------------- channel stats: sum + sumsq over node axis ----------------

template <int C>
__global__ void stats_kernel(const float* __restrict__ y, float* __restrict__ stats) {
    int tid = threadIdx.x;
    size_t stride = (size_t)gridDim.x * 256;
    size_t idx = (size_t)blockIdx.x * 256 + tid;
    float s = 0.f, s2 = 0.f;
    for (; idx < (size_t)NN * C; idx += stride) {
        float v = y[idx];
        s += v;
        s2 += v * v;
    }
    __shared__ float ls[256], ls2[256];
    ls[tid] = s; ls2[tid] = s2;
    __syncthreads();
    int c = tid & (C - 1);
    if (tid < C) {
        for (int t = tid + C; t < 256; t += C) { s += ls[t]; s2 += ls2[t]; }
        atomicAdd(&stats[c], s);
        atomicAdd(&stats[128 + c], s2);
    }
}

__global__ void bn_fin_kernel(const float* __restrict__ stats, const float* __restrict__ g,
                              const float* __restrict__ b, float* __restrict__ sb, int C) {
    int c = threadIdx.x;
    if (c < C) {
        float mu = stats[c] * (1.0f / NN);
        float var = stats[128 + c] * (1.0f / NN) - mu * mu;
        float inv = rsqrtf(var + 1e-5f);
        float sc = g[c] * inv;
        sb[c] = sc;
        sb[128 + c] = b[c] - mu * sc;
    }
}

// ---------------- BN2 + relu in-place on y2 (N x 128) ----------------

__global__ void bnrelu_kernel(float* __restrict__ a, const float* __restrict__ sb) {
    size_t i = (size_t)blockIdx.x * 256 + threadIdx.x;
    if (i >= (size_t)NN * 32) return;
    float4 v = ((float4*)a)[i];
    int c = (int)(i & 31) * 4;
    v.x = fmaxf(fmaf(v.x, sb[c + 0], sb[128 + c + 0]), 0.f);
    v.y = fmaxf(fmaf(v.y, sb[c + 1], sb[128 + c + 1]), 0.f);
    v.z = fmaxf(fmaf(v.z, sb[c + 2], sb[128 + c + 2]), 0.f);
    v.w = fmaxf(fmaf(v.w, sb[c + 3], sb[128 + c + 3]), 0.f);
    ((float4*)a)[i] = v;
}

// ---------------- mean pool over sorted batch via wave-segmented scan ----------------

__global__ void pool_accum_kernel(const float* __restrict__ xl, const int* __restrict__ batch,
                                  float* __restrict__ pool) {
    int n = blockIdx.x * 256 + threadIdx.x;
    int lane = threadIdx.x & 63;
    int g = -1;
    float v0 = 0.f, v1 = 0.f, c = 0.f;
    if (n < NN) {
        g = batch[n];
        v0 = xl[2 * n + 0];
        v1 = xl[2 * n + 1];
        c = 1.0f;
    }
    for (int d = 1; d < 64; d <<= 1) {
        int tg = __shfl_up(g, d);
        float t0 = __shfl_up(v0, d);
        float t1 = __shfl_up(v1, d);
        float tc = __shfl_up(c, d);
        if (lane >= d && tg == g) { v0 += t0; v1 += t1; c += tc; }
    }
    int gn = __shfl_down(g, 1);
    bool lastv = (lane == 63) || (gn != g);
    if (g >= 0 && lastv) {
        atomicAdd(&pool[g * 3 + 0], v0);
        atomicAdd(&pool[g * 3 + 1], v1);
        atomicAdd(&pool[g * 3 + 2], c);
    }
}

__global__ void pool_fin_kernel(const float* __restrict__ pool, float* __restrict__ out) {
    int t = threadIdx.x;
    if (t < GG * 2) {
        int g = t >> 1, j = t & 1;
        float cnt = pool[g * 3 + 2];
        out[t] = pool[g * 3 + j] / fmaxf(cnt, 1.0f);
    }
}

// ---------------- launch ----------------

extern "C" void kernel_launch(void* const* d_in, const int* in_sizes, int n_in,
                              void* d_out, int out_size, void* d_ws, size_t ws_size,
                              hipStream_t stream) {
    const float* x_in  = (const float*)d_in[0];
    const int*   ei    = (const int*)d_in[1];
    const int*   batch = (const int*)d_in[3];
    const float* W1    = (const float*)d_in[4];
    const float* bn1g  = (const float*)d_in[5];
    const float* bn1b  = (const float*)d_in[6];
    const float* W2    = (const float*)d_in[7];
    const float* bn2g  = (const float*)d_in[8];
    const float* bn2b  = (const float*)d_in[9];
    const float* Wlast = (const float*)d_in[10];
    const float* eps   = (const float*)d_in[11];
    float* out = (float*)d_out;

    char* ws = (char*)d_ws;
    size_t off = 0;
    auto alloc = [&](size_t bytes) -> char* {
        char* p = ws + off;
        off += (bytes + 255) & ~(size_t)255;
        return p;
    };
    int*   deg    = (int*)alloc((size_t)NN * 4);
    int*   offs   = (int*)alloc((size_t)(NN + 1) * 4);
    int*   cursor = (int*)alloc((size_t)NN * 4);
    int*   bsum   = (int*)alloc(64 * 4);
    int*   srcs   = (int*)alloc((size_t)EE * 4);
    float* A      = (float*)alloc((size_t)NN * 128 * 4);  // x buffer / y2 raw
    float* B      = (float*)alloc((size_t)NN * 128 * 4);  // h0
    float* Cb     = (float*)alloc((size_t)NN * 64 * 4);   // y1 raw
    float* xlast  = (float*)alloc((size_t)NN * 2 * 4);
    float* stats  = (float*)alloc(512 * 4);
    float* sb     = (float*)alloc(512 * 4);
    float* pool   = (float*)alloc((size_t)GG * 3 * 4);
    (void)ws_size; (void)n_in; (void)in_sizes; (void)out_size;

    // CSR build (by dst)
    hipMemsetAsync(deg, 0, (size_t)NN * 4, stream);
    hist_kernel<<<(EE + 255) / 256, 256, 0, stream>>>(ei, deg);
    scan1_kernel<<<49, 1024, 0, stream>>>(deg, offs, bsum);
    scan2_kernel<<<1, 64, 0, stream>>>(bsum, 49);
    scan3_kernel<<<49, 1024, 0, stream>>>(offs, cursor, bsum);
    scatter_kernel<<<(EE + 255) / 256, 256, 0, stream>>>(ei, cursor, srcs);

    for (int i = 0; i < 7; ++i) {
        const float* xcur = (i == 0) ? x_in : A;
        hipMemsetAsync(stats, 0, 512 * 4, stream);
        agg_kernel<<<(NN + 3) / 4, 256, 0, stream>>>(xcur, offs, srcs, eps, i, B);
        gemm1_kernel<<<(NN + 255) / 256, 256, 0, stream>>>(B, W1 + (size_t)i * 128 * 64, Cb);
        stats_kernel<64><<<256, 256, 0, stream>>>(Cb, stats);
        bn_fin_kernel<<<1, 64, 0, stream>>>(stats, bn1g + i * 64, bn1b + i * 64, sb, 64);
        if (i < 6) {
            gemm2_kernel<<<(NN + 255) / 256, 256, 0, stream>>>(Cb, W2 + (size_t)i * 64 * 128, sb, A);
            stats_kernel<128><<<256, 256, 0, stream>>>(A, stats + 256);
            bn_fin_kernel<<<1, 128, 0, stream>>>(stats + 256, bn2g + i * 128, bn2b + i * 128,
                                                 sb + 256, 128);
            bnrelu_kernel<<<((NN * 32) + 255) / 256, 256, 0, stream>>>(A, sb + 256);
        } else {
            gemm_last_kernel<<<(NN + 255) / 256, 256, 0, stream>>>(Cb, Wlast, sb, xlast);
        }
    }

    hipMemsetAsync(pool, 0, (size_t)GG * 3 * 4, stream);
    pool_accum_kernel<<<(NN + 255) / 256, 256, 0, stream>>>(xlast, batch, pool);
    pool_fin_kernel<<<1, 128, 0, stream>>>(pool, out);
}

// Round 2
// 1516.121 us; speedup vs baseline: 1.0415x; 1.0415x over previous
//
#include <hip/hip_runtime.h>

#define NN 50000
#define EE 800000
#define GG 64

// ---------------- CSR build ----------------

__global__ void hist_kernel(const int* __restrict__ ei, int* __restrict__ deg) {
    int e = blockIdx.x * 256 + threadIdx.x;
    if (e < EE) atomicAdd(&deg[ei[EE + e]], 1);
}

__global__ void scan1_kernel(const int* __restrict__ deg, int* __restrict__ offs,
                             int* __restrict__ bsum) {
    __shared__ int lds[1024];
    int i = blockIdx.x * 1024 + threadIdx.x;
    int v = (i < NN) ? deg[i] : 0;
    lds[threadIdx.x] = v;
    __syncthreads();
    for (int d = 1; d < 1024; d <<= 1) {
        int t = (threadIdx.x >= d) ? lds[threadIdx.x - d] : 0;
        __syncthreads();
        lds[threadIdx.x] += t;
        __syncthreads();
    }
    int incl = lds[threadIdx.x];
    if (i < NN) offs[i] = incl - v;  // exclusive within block
    if (threadIdx.x == 1023) bsum[blockIdx.x] = incl;
}

__global__ void scan2_kernel(int* bsum, int nb) {
    if (threadIdx.x == 0 && blockIdx.x == 0) {
        int run = 0;
        for (int b = 0; b < nb; ++b) { int t = bsum[b]; bsum[b] = run; run += t; }
    }
}

__global__ void scan3_kernel(int* __restrict__ offs, int* __restrict__ cursor,
                             const int* __restrict__ bsum) {
    int i = blockIdx.x * 1024 + threadIdx.x;
    if (i < NN) {
        int o = offs[i] + bsum[blockIdx.x];
        offs[i] = o;
        cursor[i] = o;
    }
    if (i == 0 && blockIdx.x == 0) offs[NN] = EE;
}

__global__ void scatter_kernel(const int* __restrict__ ei, int* __restrict__ cursor,
                               int* __restrict__ srcs) {
    int e = blockIdx.x * 256 + threadIdx.x;
    if (e < EE) {
        int s = ei[e];
        int d = ei[EE + e];
        int pos = atomicAdd(&cursor[d], 1);
        srcs[pos] = s;
    }
}

// ---------------- GIN aggregation, BN2+ReLU of previous layer fused in ----------------
// h0 = (1+eps)*f(x[node]) + sum_{src->node} f(x[src]),  f = BN? relu(bn) : identity
// one wave per node; float2/lane covers 128 dims; 8 src indices prefetched + shfl-broadcast

template <bool BN>
__global__ void agg_kernel(const float* __restrict__ x, const int* __restrict__ offs,
                           const int* __restrict__ srcs, const float* __restrict__ epsp,
                           int layer, const float* __restrict__ sb, float* __restrict__ h0) {
    int node = blockIdx.x * 4 + (threadIdx.x >> 6);
    if (node >= NN) return;
    int lane = threadIdx.x & 63;
    float2 sc, sh;
    if (BN) {
        sc = *(const float2*)(sb + 2 * lane);
        sh = *(const float2*)(sb + 128 + 2 * lane);
    }
    int beg = offs[node], end = offs[node + 1];
    float a0 = 0.f, a1 = 0.f;
    const float* xl = x + 2 * lane;
    int idx = (beg < end) ? srcs[min(beg + (lane & 7), end - 1)] : 0;
    for (int base = beg; base < end; base += 8) {
        int nb = base + 8;
        int idxn = (nb < end) ? srcs[min(nb + (lane & 7), end - 1)] : 0;
        int m = end - base;
#pragma unroll
        for (int j = 0; j < 8; ++j) {
            if (j < m) {
                int s = __shfl(idx, j);
                float2 v = *(const float2*)(xl + (size_t)s * 128);
                if (BN) {
                    v.x = fmaxf(fmaf(v.x, sc.x, sh.x), 0.f);
                    v.y = fmaxf(fmaf(v.y, sc.y, sh.y), 0.f);
                }
                a0 += v.x;
                a1 += v.y;
            }
        }
        idx = idxn;
    }
    float e1 = 1.0f + epsp[layer];
    float2 xv = *(const float2*)(xl + (size_t)node * 128);
    if (BN) {
        xv.x = fmaxf(fmaf(xv.x, sc.x, sh.x), 0.f);
        xv.y = fmaxf(fmaf(xv.y, sc.y, sh.y), 0.f);
    }
    float2 o;
    o.x = fmaf(e1, xv.x, a0);
    o.y = fmaf(e1, xv.y, a1);
    *(float2*)(h0 + (size_t)node * 128 + 2 * lane) = o;
}

// ---------------- GEMM1: y1 = h0 (N x 128) @ W (128 x 64), raw output ----------------

__global__ __launch_bounds__(256) void gemm1_kernel(const float* __restrict__ h0,
                                                    const float* __restrict__ W,
                                                    float* __restrict__ y) {
    __shared__ float lW[128 * 64];
    for (int t = threadIdx.x; t < 2048; t += 256)
        ((float4*)lW)[t] = ((const float4*)W)[t];
    __syncthreads();
    int n = blockIdx.x * 256 + threadIdx.x;
    if (n >= NN) return;
    float acc[64];
#pragma unroll
    for (int j = 0; j < 64; ++j) acc[j] = 0.f;
    const float4* xr = (const float4*)(h0 + (size_t)n * 128);
#pragma unroll 1
    for (int k4 = 0; k4 < 32; ++k4) {
        float4 xv = xr[k4];
#pragma unroll
        for (int kk = 0; kk < 4; ++kk) {
            float xk = (kk == 0) ? xv.x : (kk == 1) ? xv.y : (kk == 2) ? xv.z : xv.w;
            const float4* wr = (const float4*)(lW + (k4 * 4 + kk) * 64);
#pragma unroll
            for (int j = 0; j < 16; ++j) {
                float4 wv = wr[j];
                acc[4 * j + 0] = fmaf(xk, wv.x, acc[4 * j + 0]);
                acc[4 * j + 1] = fmaf(xk, wv.y, acc[4 * j + 1]);
                acc[4 * j + 2] = fmaf(xk, wv.z, acc[4 * j + 2]);
                acc[4 * j + 3] = fmaf(xk, wv.w, acc[4 * j + 3]);
            }
        }
    }
    float4* yr = (float4*)(y + (size_t)n * 64);
#pragma unroll
    for (int j = 0; j < 16; ++j)
        yr[j] = make_float4(acc[4 * j], acc[4 * j + 1], acc[4 * j + 2], acc[4 * j + 3]);
}

// ---------------- GEMM2: y2 = relu(bn1(y1)) (N x 64) @ W (64 x 128), raw output ----------------
// 2 threads per node, 64 output channels each

__global__ __launch_bounds__(256) void gemm2_kernel(const float* __restrict__ y1,
                                                    const float* __restrict__ W,
                                                    const float* __restrict__ sb,
                                                    float* __restrict__ y2) {
    __shared__ float lW[64 * 128];
    __shared__ float lsb[128];
    for (int t = threadIdx.x; t < 2048; t += 256)
        ((float4*)lW)[t] = ((const float4*)W)[t];
    if (threadIdx.x < 128) lsb[threadIdx.x] = sb[threadIdx.x];
    __syncthreads();
    int n = blockIdx.x * 128 + (threadIdx.x >> 1);
    int half = threadIdx.x & 1;
    if (n >= NN) return;
    float acc[64];
#pragma unroll
    for (int j = 0; j < 64; ++j) acc[j] = 0.f;
    const float4* xr = (const float4*)(y1 + (size_t)n * 64);
    const float* lWh = lW + half * 64;
#pragma unroll 1
    for (int k4 = 0; k4 < 16; ++k4) {
        float4 xv = xr[k4];
#pragma unroll
        for (int kk = 0; kk < 4; ++kk) {
            int k = k4 * 4 + kk;
            float raw = (kk == 0) ? xv.x : (kk == 1) ? xv.y : (kk == 2) ? xv.z : xv.w;
            float v = fmaxf(fmaf(raw, lsb[k], lsb[64 + k]), 0.f);
            const float4* wr = (const float4*)(lWh + k * 128);
#pragma unroll
            for (int j = 0; j < 16; ++j) {
                float4 wv = wr[j];
                acc[4 * j + 0] = fmaf(v, wv.x, acc[4 * j + 0]);
                acc[4 * j + 1] = fmaf(v, wv.y, acc[4 * j + 1]);
                acc[4 * j + 2] = fmaf(v, wv.z, acc[4 * j + 2]);
                acc[4 * j + 3] = fmaf(v, wv.w, acc[4 * j + 3]);
            }
        }
    }
    float4* yr = (float4*)(y2 + (size_t)n * 128 + half * 64);
#pragma unroll
    for (int j = 0; j < 16; ++j)
        yr[j] = make_float4(acc[4 * j], acc[4 * j + 1], acc[4 * j + 2], acc[4 * j + 3]);
}

// ---------------- last layer: x = relu( relu(bn1(y1)) @ Wlast (64 x 2) ) ----------------

__global__ void gemm_last_kernel(const float* __restrict__ y1, const float* __restrict__ W,
                                 const float* __restrict__ sb, float* __restrict__ xl) {
    __shared__ float lw[128];
    if (threadIdx.x < 128) lw[threadIdx.x] = W[threadIdx.x];
    __syncthreads();
    int n = blockIdx.x * 256 + threadIdx.x;
    if (n >= NN) return;
    float a0 = 0.f, a1 = 0.f;
    const float* row = y1 + (size_t)n * 64;
#pragma unroll
    for (int k = 0; k < 64; ++k) {
        float v = fmaxf(fmaf(row[k], sb[k], sb[64 + k]), 0.f);
        a0 = fmaf(v, lw[2 * k + 0], a0);
        a1 = fmaf(v, lw[2 * k + 1], a1);
    }
    xl[2 * n + 0] = fmaxf(a0, 0.f);
    xl[2 * n + 1] = fmaxf(a1, 0.f);
}

// ---------------- fused channel stats + BN scale/shift finalize ----------------
// stats layout per slot: [0..C) sum, [C..2C) sumsq. sb layout: [0..C) scale, [C..2C) shift.

template <int C>
__global__ void stats_fin_kernel(const float* __restrict__ y, float* __restrict__ stats,
                                 int* __restrict__ cnt, const float* __restrict__ g,
                                 const float* __restrict__ b, float* __restrict__ sb) {
    int tid = threadIdx.x;
    size_t stride = (size_t)gridDim.x * 256;
    size_t idx = (size_t)blockIdx.x * 256 + tid;
    float s = 0.f, s2 = 0.f;
    const size_t total = (size_t)NN * C;
    for (; idx < total; idx += stride) {
        float v = y[idx];
        s += v;
        s2 += v * v;
    }
    __shared__ float ls[256], ls2[256];
    ls[tid] = s;
    ls2[tid] = s2;
    __syncthreads();
    if (tid < C) {
        for (int t = tid + C; t < 256; t += C) { s += ls[t]; s2 += ls2[t]; }
        atomicAdd(&stats[tid], s);
        atomicAdd(&stats[C + tid], s2);
    }
    __threadfence();
    __syncthreads();
    __shared__ int isLast;
    if (tid == 0) isLast = (atomicAdd(cnt, 1) == (int)gridDim.x - 1);
    __syncthreads();
    if (isLast && tid < C) {
        float ss = atomicAdd(&stats[tid], 0.0f);       // coherent read
        float ss2 = atomicAdd(&stats[C + tid], 0.0f);  // coherent read
        float mu = ss * (1.0f / NN);
        float var = ss2 * (1.0f / NN) - mu * mu;
        float inv = rsqrtf(var + 1e-5f);
        float scv = g[tid] * inv;
        sb[tid] = scv;
        sb[C + tid] = b[tid] - mu * scv;
    }
}

// ---------------- mean pool over sorted batch via wave-segmented scan ----------------

__global__ void pool_accum_kernel(const float* __restrict__ xl, const int* __restrict__ batch,
                                  float* __restrict__ pool) {
    int n = blockIdx.x * 256 + threadIdx.x;
    int lane = threadIdx.x & 63;
    int g = -1;
    float v0 = 0.f, v1 = 0.f, c = 0.f;
    if (n < NN) {
        g = batch[n];
        v0 = xl[2 * n + 0];
        v1 = xl[2 * n + 1];
        c = 1.0f;
    }
    for (int d = 1; d < 64; d <<= 1) {
        int tg = __shfl_up(g, d);
        float t0 = __shfl_up(v0, d);
        float t1 = __shfl_up(v1, d);
        float tc = __shfl_up(c, d);
        if (lane >= d && tg == g) { v0 += t0; v1 += t1; c += tc; }
    }
    int gn = __shfl_down(g, 1);
    bool lastv = (lane == 63) || (gn != g);
    if (g >= 0 && lastv) {
        atomicAdd(&pool[g * 3 + 0], v0);
        atomicAdd(&pool[g * 3 + 1], v1);
        atomicAdd(&pool[g * 3 + 2], c);
    }
}

__global__ void pool_fin_kernel(const float* __restrict__ pool, float* __restrict__ out) {
    int t = threadIdx.x;
    if (t < GG * 2) {
        int g = t >> 1, j = t & 1;
        float cnt = pool[g * 3 + 2];
        out[t] = pool[g * 3 + j] / fmaxf(cnt, 1.0f);
    }
}

// ---------------- launch ----------------

extern "C" void kernel_launch(void* const* d_in, const int* in_sizes, int n_in,
                              void* d_out, int out_size, void* d_ws, size_t ws_size,
                              hipStream_t stream) {
    const float* x_in  = (const float*)d_in[0];
    const int*   ei    = (const int*)d_in[1];
    const int*   batch = (const int*)d_in[3];
    const float* W1    = (const float*)d_in[4];
    const float* bn1g  = (const float*)d_in[5];
    const float* bn1b  = (const float*)d_in[6];
    const float* W2    = (const float*)d_in[7];
    const float* bn2g  = (const float*)d_in[8];
    const float* bn2b  = (const float*)d_in[9];
    const float* Wlast = (const float*)d_in[10];
    const float* eps   = (const float*)d_in[11];
    float* out = (float*)d_out;

    char* ws = (char*)d_ws;
    size_t off = 0;
    auto alloc = [&](size_t bytes) -> char* {
        char* p = ws + off;
        off += (bytes + 255) & ~(size_t)255;
        return p;
    };
    // -- zeroed region first (one memset) --
    int*   deg      = (int*)alloc((size_t)NN * 4);
    float* statsall = (float*)alloc(16 * 256 * 4);  // slot s: stats for dispatch s
    int*   cnts     = (int*)alloc(16 * 4);
    float* pool     = (float*)alloc((size_t)GG * 3 * 4);
    size_t zero_len = off;
    // -- rest --
    float* sball  = (float*)alloc(16 * 256 * 4);  // slot s: scale/shift
    int*   offs   = (int*)alloc((size_t)(NN + 1) * 4);
    int*   cursor = (int*)alloc((size_t)NN * 4);
    int*   bsum   = (int*)alloc(64 * 4);
    int*   srcs   = (int*)alloc((size_t)EE * 4);
    float* A      = (float*)alloc((size_t)NN * 128 * 4);  // raw y2 (gather source for next layer)
    float* B      = (float*)alloc((size_t)NN * 128 * 4);  // h0
    float* Cb     = (float*)alloc((size_t)NN * 64 * 4);   // raw y1
    float* xlast  = (float*)alloc((size_t)NN * 2 * 4);
    (void)ws_size; (void)n_in; (void)in_sizes; (void)out_size;

    hipMemsetAsync(ws, 0, zero_len, stream);

    // CSR build (by dst)
    hist_kernel<<<(EE + 255) / 256, 256, 0, stream>>>(ei, deg);
    scan1_kernel<<<49, 1024, 0, stream>>>(deg, offs, bsum);
    scan2_kernel<<<1, 64, 0, stream>>>(bsum, 49);
    scan3_kernel<<<49, 1024, 0, stream>>>(offs, cursor, bsum);
    scatter_kernel<<<(EE + 255) / 256, 256, 0, stream>>>(ei, cursor, srcs);

    for (int i = 0; i < 7; ++i) {
        int s1 = 2 * i, s2 = 2 * i + 1;
        if (i == 0) {
            agg_kernel<false><<<(NN + 3) / 4, 256, 0, stream>>>(x_in, offs, srcs, eps, i,
                                                                nullptr, B);
        } else {
            agg_kernel<true><<<(NN + 3) / 4, 256, 0, stream>>>(A, offs, srcs, eps, i,
                                                               sball + (2 * i - 1) * 256, B);
        }
        gemm1_kernel<<<(NN + 255) / 256, 256, 0, stream>>>(B, W1 + (size_t)i * 128 * 64, Cb);
        stats_fin_kernel<64><<<256, 256, 0, stream>>>(Cb, statsall + s1 * 256, cnts + s1,
                                                      bn1g + i * 64, bn1b + i * 64,
                                                      sball + s1 * 256);
        if (i < 6) {
            gemm2_kernel<<<(NN + 127) / 128, 256, 0, stream>>>(Cb, W2 + (size_t)i * 64 * 128,
                                                               sball + s1 * 256, A);
            stats_fin_kernel<128><<<256, 256, 0, stream>>>(A, statsall + s2 * 256, cnts + s2,
                                                           bn2g + i * 128, bn2b + i * 128,
                                                           sball + s2 * 256);
        } else {
            gemm_last_kernel<<<(NN + 255) / 256, 256, 0, stream>>>(Cb, Wlast,
                                                                   sball + s1 * 256, xlast);
        }
    }

    pool_accum_kernel<<<(NN + 255) / 256, 256, 0, stream>>>(xlast, batch, pool);
    pool_fin_kernel<<<1, 128, 0, stream>>>(pool, out);
}